// Round 4
// baseline (11264.809 us; speedup 1.0000x reference)
//
#include <hip/hip_runtime.h>
#include <hip/hip_bf16.h>

// GRU, T=512 B=64 D=512 H=1024.
// Round 4: persistent kernel, NO agent fences. Cross-WG data goes through the
// LLC via agent-scope relaxed atomics (sc0/sc1 cache-bypass); release ordering
// by s_waitcnt vmcnt(0); single-stage all-observe flag barrier.
// h: fp32 master lives in phase-2 registers; bf16 publish (hb) is the only
// memory-resident h. Tiling/LDS identical to round 3.

typedef __attribute__((ext_vector_type(8))) short bf16x8;
typedef __attribute__((ext_vector_type(4))) float f32x4;

#define NWG 128
#define TSTEPS 512

#define AT_LD(p) __hip_atomic_load((p), __ATOMIC_RELAXED, __HIP_MEMORY_SCOPE_AGENT)
#define AT_ST(p, v) __hip_atomic_store((p), (v), __ATOMIC_RELAXED, __HIP_MEMORY_SCOPE_AGENT)

static __device__ __forceinline__ float sigmoidf_fast(float x) {
    return 1.0f / (1.0f + __expf(-x));
}

static __device__ __forceinline__ float bf16bits_to_float(unsigned short us) {
    unsigned x = ((unsigned)us) << 16;
    float f;
    __builtin_memcpy(&f, &x, 4);
    return f;
}

static __device__ __forceinline__ unsigned short float_to_bf16bits(float f) {
    __hip_bfloat16 b = __float2bfloat16(f);
    unsigned short us;
    __builtin_memcpy(&us, &b, 2);
    return us;
}

// coherent 2-byte store (write-through to LLC)
static __device__ __forceinline__ void store_coh_u16(void* p, unsigned short v) {
    unsigned vv = v;
    asm volatile("global_store_short %0, %1, off sc0 sc1"
                 :: "v"(p), "v"(vv) : "memory");
}

union U128 { unsigned long long u[2]; bf16x8 v; };

// coherent 16-byte fragment load as 2x 8B agent atomics (bypass stale L1/L2)
static __device__ __forceinline__ bf16x8 load_coh_frag(const short* p) {
    U128 t;
    t.u[0] = AT_LD((const unsigned long long*)p);
    t.u[1] = AT_LD((const unsigned long long*)(p + 4));
    return t.v;
}

__global__ __launch_bounds__(256) void k_convert_weights(
    const float* __restrict__ Wz, const float* __restrict__ Wr,
    const float* __restrict__ Wc,
    __hip_bfloat16* __restrict__ Wzr, __hip_bfloat16* __restrict__ Wcb)
{
    const long long NW = 1024LL * 1536LL;
    const long long stride = (long long)gridDim.x * blockDim.x;
    for (long long i = (long long)blockIdx.x * blockDim.x + threadIdx.x;
         i < 3 * NW; i += stride) {
        if (i < NW)            Wzr[i] = __float2bfloat16(Wz[i]);
        else if (i < 2 * NW)   Wzr[i] = __float2bfloat16(Wr[i - NW]);
        else                   Wcb[i - 2 * NW] = __float2bfloat16(Wc[i - 2 * NW]);
    }
}

__global__ __launch_bounds__(256) void k_convert_x(
    const float* __restrict__ x, __hip_bfloat16* __restrict__ xb)
{
    const long long N = 512LL * 64LL * 512LL;
    const long long stride = (long long)gridDim.x * blockDim.x;
    for (long long i = (long long)blockIdx.x * blockDim.x + threadIdx.x;
         i < N; i += stride)
        xb[i] = __float2bfloat16(x[i]);
}

__global__ __launch_bounds__(256) void k_init_h(
    const float* __restrict__ h0, __hip_bfloat16* __restrict__ hb)
{
    int i = blockIdx.x * blockDim.x + threadIdx.x;  // grid covers 64*1024
    hb[i] = __float2bfloat16(h0[i]);
}

// Full barrier, no fences: post own flag (after vmcnt drain), wave0 polls all.
static __device__ __forceinline__ void barrier_all(
    unsigned* flags, int g, int lane, int wave, unsigned gen)
{
    asm volatile("s_waitcnt vmcnt(0)" ::: "memory");  // per-wave release drain
    __syncthreads();                                  // all waves drained
    if (threadIdx.x == 0)
        AT_ST(flags + g, gen);
    if (wave == 0) {
        bool ok = false;
        do {
            unsigned a = AT_LD(flags + lane);
            unsigned b = AT_LD(flags + 64 + lane);
            ok = (a >= gen) & (b >= gen);
        } while (__any(!ok));
    }
    __syncthreads();
    asm volatile("" ::: "memory");
}

// Persistent GRU: 128 WGs x 256 threads, 1 WG/CU (96KB LDS).
// Phase 1: WG g owns fused z|r cols [16g,16g+16); wave w owns batch [16w,16w+16).
// Phase 2: WG g owns cand cols [16*(g>>1),+16), batch half (g&1); waves 0,1 compute.
__global__ __launch_bounds__(256) void k_gru_persistent(
    const __hip_bfloat16* __restrict__ xb,   // [512][64][512]
    const float* __restrict__ h0,            // [64][1024]
    __hip_bfloat16* __restrict__ hb_,        // [64][1024] bf16 publish of h
    const __hip_bfloat16* __restrict__ Wzr,  // [2048][1536]
    const __hip_bfloat16* __restrict__ Wcb,  // [1024][1536]
    const float* __restrict__ bz, const float* __restrict__ br,
    const float* __restrict__ bc,
    float* __restrict__ zf,                  // [64][1024] z gate (coherent)
    __hip_bfloat16* __restrict__ sb_,        // [64][1024] s = r*h (coherent)
    float* __restrict__ out,                 // [512][64][1024]
    unsigned* __restrict__ flags)            // [128]
{
    __shared__ short w1[16 * 1536];  // 48KB phase-1 weight slice (swizzled)
    __shared__ short w2[16 * 1536];  // 48KB phase-2 weight slice (swizzled)

    short* hb = (short*)hb_;
    short* sb = (short*)sb_;

    const int g = blockIdx.x;
    const int lane = threadIdx.x & 63;
    const int wave = threadIdx.x >> 6;
    const int r15 = lane & 15;
    const int q = lane >> 4;        // 0..3
    const int kk = q << 3;          // per-lane K offset (8 elems)
    const int sw = r15 & 7;         // read-side LDS swizzle

    // ---- stage weight slices into LDS (once), blk^(row&7) swizzle
    for (int c = threadIdx.x; c < 16 * 192; c += 256) {
        int row = c / 192, blk = c % 192;
        bf16x8 v = *(const bf16x8*)((const short*)Wzr +
                                    (long long)(g * 16 + row) * 1536 + blk * 8);
        *(bf16x8*)(w1 + (row * 192 + (blk ^ (row & 7))) * 8) = v;
    }
    for (int c = threadIdx.x; c < 16 * 192; c += 256) {
        int row = c / 192, blk = c % 192;
        bf16x8 v = *(const bf16x8*)((const short*)Wcb +
                                    (long long)((g >> 1) * 16 + row) * 1536 + blk * 8);
        *(bf16x8*)(w2 + (row * 192 + (blk ^ (row & 7))) * 8) = v;
    }
    __syncthreads();

    // ---- per-lane constants
    const int m0 = wave << 4;                   // phase-1 batch base
    const int nc1 = g * 16 + r15;               // phase-1 fused out col
    const float bias1 = (g < 64) ? bz[nc1] : br[nc1 - 1024];
    const int nc2 = (g >> 1) * 16 + r15;        // phase-2 out col
    const float bias2 = bc[nc2];
    const int mb2 = (g & 1) * 32 + wave * 16;   // phase-2 batch base (waves 0,1)
    const int mbase1 = m0 + (q << 2);
    const int mbase2 = mb2 + (q << 2);

    // ---- phase-2 fp32 h master in registers (this WG owns (mbase2+v, nc2))
    float hreg[4];
    if (wave < 2) {
#pragma unroll
        for (int v = 0; v < 4; ++v)
            hreg[v] = h0[(mbase2 + v) * 1024 + nc2];
    }

    for (int t = 0; t < TSTEPS; ++t) {
        const short* xt = (const short*)xb + (long long)t * 64 * 512;

        // ================= Phase 1: z,r gates =================
        {
            // r-branch: prefetch h (bf16, coherent 4B pair loads)
            float hv[4];
            if (g >= 64) {
                const int nr = nc1 - 1024;
#pragma unroll
                for (int v = 0; v < 4; ++v) {
                    const unsigned* hp = (const unsigned*)
                        (hb + (mbase1 + v) * 1024 + (nr & ~1));
                    unsigned u = AT_LD(hp);
                    unsigned short us = (nr & 1) ? (unsigned short)(u >> 16)
                                                 : (unsigned short)(u & 0xffff);
                    hv[v] = bf16bits_to_float(us);
                }
            }

            const short* Ax = xt + (m0 + r15) * 512 + kk;
            const short* Ah = hb + (m0 + r15) * 1024 + kk;
            f32x4 acc = {0.f, 0.f, 0.f, 0.f};
#pragma unroll 8
            for (int ki = 0; ki < 16; ++ki) {    // K = 0..511 (x, cached loads)
                bf16x8 a = *(const bf16x8*)(Ax + ki * 32);
                bf16x8 w = *(const bf16x8*)(w1 + (r15 * 192 + ((ki * 4 + q) ^ sw)) * 8);
                acc = __builtin_amdgcn_mfma_f32_16x16x32_bf16(a, w, acc, 0, 0, 0);
            }
#pragma unroll 8
            for (int ki = 16; ki < 48; ++ki) {   // K = 512..1535 (h, coherent)
                bf16x8 a = load_coh_frag(Ah + (ki - 16) * 32);
                bf16x8 w = *(const bf16x8*)(w1 + (r15 * 192 + ((ki * 4 + q) ^ sw)) * 8);
                acc = __builtin_amdgcn_mfma_f32_16x16x32_bf16(a, w, acc, 0, 0, 0);
            }
            if (g < 64) {  // z gate -> zf (coherent f32 stores)
#pragma unroll
                for (int v = 0; v < 4; ++v) {
                    int bm = mbase1 + v;
                    AT_ST(zf + bm * 1024 + nc1, sigmoidf_fast(acc[v] + bias1));
                }
            } else {       // r gate -> s = r*h (coherent bf16 stores)
                const int nr = nc1 - 1024;
#pragma unroll
                for (int v = 0; v < 4; ++v) {
                    int bm = mbase1 + v;
                    float rg = sigmoidf_fast(acc[v] + bias1);
                    store_coh_u16(sb + bm * 1024 + nr,
                                  float_to_bf16bits(rg * hv[v]));
                }
            }
        }
        barrier_all(flags, g, lane, wave, 2 * t + 1);

        // ================= Phase 2: candidate + blend =================
        if (wave < 2) {
            // prefetch z (coherent)
            float zv[4];
#pragma unroll
            for (int v = 0; v < 4; ++v)
                zv[v] = AT_LD(zf + (mbase2 + v) * 1024 + nc2);

            const short* Ax = xt + (mb2 + r15) * 512 + kk;
            const short* As = sb + (mb2 + r15) * 1024 + kk;
            f32x4 acc = {0.f, 0.f, 0.f, 0.f};
#pragma unroll 8
            for (int ki = 0; ki < 16; ++ki) {    // K = 0..511 (x, cached)
                bf16x8 a = *(const bf16x8*)(Ax + ki * 32);
                bf16x8 w = *(const bf16x8*)(w2 + (r15 * 192 + ((ki * 4 + q) ^ sw)) * 8);
                acc = __builtin_amdgcn_mfma_f32_16x16x32_bf16(a, w, acc, 0, 0, 0);
            }
#pragma unroll 8
            for (int ki = 16; ki < 48; ++ki) {   // K = 512..1535 (s, coherent)
                bf16x8 a = load_coh_frag(As + (ki - 16) * 32);
                bf16x8 w = *(const bf16x8*)(w2 + (r15 * 192 + ((ki * 4 + q) ^ sw)) * 8);
                acc = __builtin_amdgcn_mfma_f32_16x16x32_bf16(a, w, acc, 0, 0, 0);
            }
            float* outt = out + (long long)t * 64 * 1024;
#pragma unroll
            for (int v = 0; v < 4; ++v) {
                int bm = mbase2 + v;
                float c = tanhf(acc[v] + bias2);
                float h_new = (1.0f - zv[v]) * hreg[v] + zv[v] * c;
                outt[bm * 1024 + nc2] = h_new;            // normal store
                hreg[v] = h_new;                           // register master
                store_coh_u16(hb + bm * 1024 + nc2,        // bf16 publish
                              float_to_bf16bits(h_new));
            }
        }
        if (t != TSTEPS - 1)
            barrier_all(flags, g, lane, wave, 2 * t + 2);
    }
}

extern "C" void kernel_launch(void* const* d_in, const int* in_sizes, int n_in,
                              void* d_out, int out_size, void* d_ws, size_t ws_size,
                              hipStream_t stream)
{
    (void)in_sizes; (void)n_in; (void)out_size; (void)ws_size;
    const float* x  = (const float*)d_in[0];
    const float* h0 = (const float*)d_in[1];
    const float* Wz = (const float*)d_in[2];
    const float* bz = (const float*)d_in[3];
    const float* Wr = (const float*)d_in[4];
    const float* br = (const float*)d_in[5];
    const float* Wc = (const float*)d_in[6];
    const float* bc = (const float*)d_in[7];
    float* out = (float*)d_out;

    // ws layout (bytes, 256-aligned): total ~43.6 MB
    char* ws = (char*)d_ws;
    __hip_bfloat16* Wzr = (__hip_bfloat16*)(ws);              // [2048][1536] bf16
    __hip_bfloat16* Wcb = (__hip_bfloat16*)(ws + 6291456);    // [1024][1536] bf16
    __hip_bfloat16* xb  = (__hip_bfloat16*)(ws + 9437184);    // [512][64][512] bf16
    __hip_bfloat16* hb  = (__hip_bfloat16*)(ws + 42991616);   // [64][1024] bf16
    __hip_bfloat16* sb  = (__hip_bfloat16*)(ws + 43122688);   // [64][1024] bf16
    float*          zf  = (float*)(ws + 43253760);            // [64][1024] f32
    unsigned*    flags  = (unsigned*)(ws + 43515904);         // [128]

    k_convert_weights<<<1024, 256, 0, stream>>>(Wz, Wr, Wc, Wzr, Wcb);
    k_convert_x<<<2048, 256, 0, stream>>>(x, xb);
    k_init_h<<<256, 256, 0, stream>>>(h0, hb);
    (void)hipMemsetAsync(flags, 0, NWG * sizeof(unsigned), stream);

    k_gru_persistent<<<NWG, 256, 0, stream>>>(
        xb, h0, hb, Wzr, Wcb, bz, br, bc, zf, sb, out, flags);
}

// Round 5
// 7464.130 us; speedup vs baseline: 1.5092x; 1.5092x over previous
//
#include <hip/hip_runtime.h>
#include <hip/hip_bf16.h>

// GRU, T=512 B=64 D=512 H=1024.
// Round 5: persistent kernel; batched asm coherent loads (sc0 sc1) for the
// recurrent K-part (2 LLC round-trips/phase instead of ~32 serialized atomic
// loads); x-part MFMAs hoisted before the barrier wait; single-atomic-counter
// grid barrier. bf16 MFMA, fp32 accumulate, fp32 h master in registers.

typedef __attribute__((ext_vector_type(8))) short bf16x8;
typedef __attribute__((ext_vector_type(4))) float f32x4;

#define NWG 128
#define TSTEPS 512

#define AT_LD(p) __hip_atomic_load((p), __ATOMIC_RELAXED, __HIP_MEMORY_SCOPE_AGENT)
#define AT_ST(p, v) __hip_atomic_store((p), (v), __ATOMIC_RELAXED, __HIP_MEMORY_SCOPE_AGENT)

static __device__ __forceinline__ float sigmoidf_fast(float x) {
    return 1.0f / (1.0f + __expf(-x));
}

static __device__ __forceinline__ float bf16bits_to_float(unsigned short us) {
    unsigned x = ((unsigned)us) << 16;
    float f;
    __builtin_memcpy(&f, &x, 4);
    return f;
}

static __device__ __forceinline__ unsigned short float_to_bf16bits(float f) {
    __hip_bfloat16 b = __float2bfloat16(f);
    unsigned short us;
    __builtin_memcpy(&us, &b, 2);
    return us;
}

// coherent 2-byte store (write-through to LLC)
static __device__ __forceinline__ void store_coh_u16(void* p, unsigned short v) {
    unsigned vv = v;
    asm volatile("global_store_short %0, %1, off sc0 sc1"
                 :: "v"(p), "v"(vv) : "memory");
}

__global__ __launch_bounds__(256) void k_convert_weights(
    const float* __restrict__ Wz, const float* __restrict__ Wr,
    const float* __restrict__ Wc,
    __hip_bfloat16* __restrict__ Wzr, __hip_bfloat16* __restrict__ Wcb)
{
    const long long NW = 1024LL * 1536LL;
    const long long stride = (long long)gridDim.x * blockDim.x;
    for (long long i = (long long)blockIdx.x * blockDim.x + threadIdx.x;
         i < 3 * NW; i += stride) {
        if (i < NW)            Wzr[i] = __float2bfloat16(Wz[i]);
        else if (i < 2 * NW)   Wzr[i] = __float2bfloat16(Wr[i - NW]);
        else                   Wcb[i - 2 * NW] = __float2bfloat16(Wc[i - 2 * NW]);
    }
}

__global__ __launch_bounds__(256) void k_convert_x(
    const float* __restrict__ x, __hip_bfloat16* __restrict__ xb)
{
    const long long N = 512LL * 64LL * 512LL;
    const long long stride = (long long)gridDim.x * blockDim.x;
    for (long long i = (long long)blockIdx.x * blockDim.x + threadIdx.x;
         i < N; i += stride)
        xb[i] = __float2bfloat16(x[i]);
}

__global__ __launch_bounds__(256) void k_init_h(
    const float* __restrict__ h0, __hip_bfloat16* __restrict__ hb)
{
    int i = blockIdx.x * blockDim.x + threadIdx.x;  // grid covers 64*1024
    hb[i] = __float2bfloat16(h0[i]);
}

// ---- grid barrier: single monotone atomic counter at the LLC ----
static __device__ __forceinline__ void bar_arrive(unsigned* cnt) {
    asm volatile("s_waitcnt vmcnt(0)" ::: "memory");  // drain this wave's stores
    __syncthreads();                                  // all waves drained
    if (threadIdx.x == 0) atomicAdd(cnt, 1u);         // device-scope [m20]
}
static __device__ __forceinline__ void bar_wait(unsigned* cnt, unsigned target) {
    if (threadIdx.x == 0) {
        while (AT_LD(cnt) < target) {}
    }
    __syncthreads();
    asm volatile("" ::: "memory");
}

// Persistent GRU: 128 WGs x 256 threads, 1 WG/CU (96KB LDS).
// Phase 1: WG g owns fused z|r cols [16g,16g+16); wave w owns batch [16w,16w+16).
// Phase 2: WG g owns cand cols [16*(g>>1),+16), batch half (g&1); waves 0,1.
__global__ __launch_bounds__(256) void k_gru_persistent(
    const __hip_bfloat16* __restrict__ xb,   // [512][64][512]
    const float* __restrict__ h0,            // [64][1024]
    __hip_bfloat16* __restrict__ hb_,        // [64][1024] bf16 publish of h
    const __hip_bfloat16* __restrict__ Wzr,  // [2048][1536]
    const __hip_bfloat16* __restrict__ Wcb,  // [1024][1536]
    const float* __restrict__ bz, const float* __restrict__ br,
    const float* __restrict__ bc,
    float* __restrict__ zf,                  // [64][1024] z gate (coherent)
    __hip_bfloat16* __restrict__ sb_,        // [64][1024] s = r*h (coherent)
    float* __restrict__ out,                 // [512][64][1024]
    unsigned* __restrict__ cnt)              // barrier counter
{
    __shared__ short w1[16 * 1536];  // 48KB phase-1 weight slice (swizzled)
    __shared__ short w2[16 * 1536];  // 48KB phase-2 weight slice (swizzled)

    short* hb = (short*)hb_;
    short* sb = (short*)sb_;

    const int g = blockIdx.x;
    const int lane = threadIdx.x & 63;
    const int wave = threadIdx.x >> 6;
    const int r15 = lane & 15;
    const int q = lane >> 4;        // 0..3
    const int kk = q << 3;          // per-lane K offset (8 elems)
    const int sw = r15 & 7;         // read-side LDS swizzle
    (void)lane;

    // ---- stage weight slices into LDS (once), blk^(row&7) swizzle
    for (int c = threadIdx.x; c < 16 * 192; c += 256) {
        int row = c / 192, blk = c % 192;
        bf16x8 v = *(const bf16x8*)((const short*)Wzr +
                                    (long long)(g * 16 + row) * 1536 + blk * 8);
        *(bf16x8*)(w1 + (row * 192 + (blk ^ (row & 7))) * 8) = v;
    }
    for (int c = threadIdx.x; c < 16 * 192; c += 256) {
        int row = c / 192, blk = c % 192;
        bf16x8 v = *(const bf16x8*)((const short*)Wcb +
                                    (long long)((g >> 1) * 16 + row) * 1536 + blk * 8);
        *(bf16x8*)(w2 + (row * 192 + (blk ^ (row & 7))) * 8) = v;
    }
    __syncthreads();

    // ---- per-lane constants
    const int m0 = wave << 4;                   // phase-1 batch base
    const int nc1 = g * 16 + r15;               // phase-1 fused out col
    const float bias1 = (g < 64) ? bz[nc1] : br[nc1 - 1024];
    const int nc2 = (g >> 1) * 16 + r15;        // phase-2 out col
    const float bias2 = bc[nc2];
    const int mb2 = (g & 1) * 32 + wave * 16;   // phase-2 batch base (waves 0,1)
    const int mbase1 = m0 + (q << 2);
    const int mbase2 = mb2 + (q << 2);

    // ---- phase-2 fp32 h master in registers (this WG owns (mbase2+v, nc2))
    float hreg[4];
    if (wave < 2) {
#pragma unroll
        for (int v = 0; v < 4; ++v)
            hreg[v] = h0[(mbase2 + v) * 1024 + nc2];
    }

    for (int t = 0; t < TSTEPS; ++t) {
        const short* xt = (const short*)xb + (long long)t * 64 * 512;

        // ======== Phase 1: x-part (before wait — overlaps barrier) ========
        f32x4 accA = {0.f, 0.f, 0.f, 0.f};
        f32x4 accB = {0.f, 0.f, 0.f, 0.f};
        {
            const short* Ax = xt + (m0 + r15) * 512 + kk;
#pragma unroll
            for (int ki = 0; ki < 16; ++ki) {
                bf16x8 a = *(const bf16x8*)(Ax + ki * 32);
                bf16x8 w = *(const bf16x8*)(w1 + (r15 * 192 + ((ki * 4 + q) ^ sw)) * 8);
                if (ki & 1)
                    accB = __builtin_amdgcn_mfma_f32_16x16x32_bf16(a, w, accB, 0, 0, 0);
                else
                    accA = __builtin_amdgcn_mfma_f32_16x16x32_bf16(a, w, accA, 0, 0, 0);
            }
        }
        bar_wait(cnt, (unsigned)(2 * t) * NWG);   // h(t-1) published

        // ---- r-branch h prefetch (coherent, drained by first batch waitcnt)
        float hv[4];
        if (g >= 64) {
            const int nr = nc1 - 1024;
#pragma unroll
            for (int v = 0; v < 4; ++v) {
                const unsigned* hp = (const unsigned*)
                    (hb + (mbase1 + v) * 1024 + (nr & ~1));
                unsigned u = AT_LD(hp);
                unsigned short us = (nr & 1) ? (unsigned short)(u >> 16)
                                             : (unsigned short)(u & 0xffff);
                hv[v] = bf16bits_to_float(us);
            }
        }

        // ---- h-part: 2 batches of 16 coherent b128 loads + 16 MFMAs
        {
            const short* Ah = hb + (m0 + r15) * 1024 + kk;
            bf16x8 fr[16];
#pragma unroll
            for (int b = 0; b < 2; ++b) {
#pragma unroll
                for (int i = 0; i < 16; ++i)
                    asm volatile("global_load_dwordx4 %0, %1, off sc0 sc1"
                                 : "=v"(fr[i]) : "v"(Ah + (b * 16 + i) * 32));
                asm volatile("s_waitcnt vmcnt(0)" ::: "memory");
                __builtin_amdgcn_sched_barrier(0);
#pragma unroll
                for (int i = 0; i < 16; ++i) {
                    int ki = 16 + b * 16 + i;
                    bf16x8 w = *(const bf16x8*)(w1 + (r15 * 192 + ((ki * 4 + q) ^ sw)) * 8);
                    if (i & 1)
                        accB = __builtin_amdgcn_mfma_f32_16x16x32_bf16(fr[i], w, accB, 0, 0, 0);
                    else
                        accA = __builtin_amdgcn_mfma_f32_16x16x32_bf16(fr[i], w, accA, 0, 0, 0);
                }
            }
        }
        {
            f32x4 acc = accA + accB;
            if (g < 64) {  // z gate -> zf (coherent f32 stores)
#pragma unroll
                for (int v = 0; v < 4; ++v)
                    AT_ST(zf + (mbase1 + v) * 1024 + nc1,
                          sigmoidf_fast(acc[v] + bias1));
            } else {       // r gate -> s = r*h (coherent bf16 stores)
                const int nr = nc1 - 1024;
#pragma unroll
                for (int v = 0; v < 4; ++v) {
                    float rg = sigmoidf_fast(acc[v] + bias1);
                    store_coh_u16(sb + (mbase1 + v) * 1024 + nr,
                                  float_to_bf16bits(rg * hv[v]));
                }
            }
        }
        bar_arrive(cnt);                          // -> 128*(2t+1)

        // ======== Phase 2: x-part (before wait) ========
        f32x4 acc2A = {0.f, 0.f, 0.f, 0.f};
        f32x4 acc2B = {0.f, 0.f, 0.f, 0.f};
        if (wave < 2) {
            const short* Ax = xt + (mb2 + r15) * 512 + kk;
#pragma unroll
            for (int ki = 0; ki < 16; ++ki) {
                bf16x8 a = *(const bf16x8*)(Ax + ki * 32);
                bf16x8 w = *(const bf16x8*)(w2 + (r15 * 192 + ((ki * 4 + q) ^ sw)) * 8);
                if (ki & 1)
                    acc2B = __builtin_amdgcn_mfma_f32_16x16x32_bf16(a, w, acc2B, 0, 0, 0);
                else
                    acc2A = __builtin_amdgcn_mfma_f32_16x16x32_bf16(a, w, acc2A, 0, 0, 0);
            }
        }
        bar_wait(cnt, (unsigned)(2 * t + 1) * NWG);  // z, s published

        if (wave < 2) {
            // z prefetch (coherent, drained by first batch waitcnt)
            float zv[4];
#pragma unroll
            for (int v = 0; v < 4; ++v)
                zv[v] = AT_LD(zf + (mbase2 + v) * 1024 + nc2);

            const short* As = sb + (mb2 + r15) * 1024 + kk;
            bf16x8 fr[16];
#pragma unroll
            for (int b = 0; b < 2; ++b) {
#pragma unroll
                for (int i = 0; i < 16; ++i)
                    asm volatile("global_load_dwordx4 %0, %1, off sc0 sc1"
                                 : "=v"(fr[i]) : "v"(As + (b * 16 + i) * 32));
                asm volatile("s_waitcnt vmcnt(0)" ::: "memory");
                __builtin_amdgcn_sched_barrier(0);
#pragma unroll
                for (int i = 0; i < 16; ++i) {
                    int ki = 16 + b * 16 + i;
                    bf16x8 w = *(const bf16x8*)(w2 + (r15 * 192 + ((ki * 4 + q) ^ sw)) * 8);
                    if (i & 1)
                        acc2B = __builtin_amdgcn_mfma_f32_16x16x32_bf16(fr[i], w, acc2B, 0, 0, 0);
                    else
                        acc2A = __builtin_amdgcn_mfma_f32_16x16x32_bf16(fr[i], w, acc2A, 0, 0, 0);
                }
            }
            f32x4 acc = acc2A + acc2B;
            float* outt = out + (long long)t * 64 * 1024;
#pragma unroll
            for (int v = 0; v < 4; ++v) {
                int bm = mbase2 + v;
                float c = tanhf(acc[v] + bias2);
                float h_new = (1.0f - zv[v]) * hreg[v] + zv[v] * c;
                outt[bm * 1024 + nc2] = h_new;            // plain store (HBM)
                hreg[v] = h_new;                           // register master
                store_coh_u16(hb + bm * 1024 + nc2,        // bf16 publish
                              float_to_bf16bits(h_new));
            }
        }
        bar_arrive(cnt);                          // -> 128*(2t+2)
    }
}

extern "C" void kernel_launch(void* const* d_in, const int* in_sizes, int n_in,
                              void* d_out, int out_size, void* d_ws, size_t ws_size,
                              hipStream_t stream)
{
    (void)in_sizes; (void)n_in; (void)out_size; (void)ws_size;
    const float* x  = (const float*)d_in[0];
    const float* h0 = (const float*)d_in[1];
    const float* Wz = (const float*)d_in[2];
    const float* bz = (const float*)d_in[3];
    const float* Wr = (const float*)d_in[4];
    const float* br = (const float*)d_in[5];
    const float* Wc = (const float*)d_in[6];
    const float* bc = (const float*)d_in[7];
    float* out = (float*)d_out;

    // ws layout (bytes, 256-aligned): total ~43.6 MB
    char* ws = (char*)d_ws;
    __hip_bfloat16* Wzr = (__hip_bfloat16*)(ws);              // [2048][1536] bf16
    __hip_bfloat16* Wcb = (__hip_bfloat16*)(ws + 6291456);    // [1024][1536] bf16
    __hip_bfloat16* xb  = (__hip_bfloat16*)(ws + 9437184);    // [512][64][512] bf16
    __hip_bfloat16* hb  = (__hip_bfloat16*)(ws + 42991616);   // [64][1024] bf16
    __hip_bfloat16* sb  = (__hip_bfloat16*)(ws + 43122688);   // [64][1024] bf16
    float*          zf  = (float*)(ws + 43253760);            // [64][1024] f32
    unsigned*       cnt = (unsigned*)(ws + 43515904);         // barrier counter

    k_convert_weights<<<1024, 256, 0, stream>>>(Wz, Wr, Wc, Wzr, Wcb);
    k_convert_x<<<2048, 256, 0, stream>>>(x, xb);
    k_init_h<<<256, 256, 0, stream>>>(h0, hb);
    (void)hipMemsetAsync(cnt, 0, sizeof(unsigned), stream);

    k_gru_persistent<<<NWG, 256, 0, stream>>>(
        xb, h0, hb, Wzr, Wcb, bz, br, bc, zf, sb, out, cnt);
}